// Round 10
// baseline (314.769 us; speedup 1.0000x reference)
//
#include <hip/hip_runtime.h>
#include <hip/hip_fp16.h>

// QuantizedLinearWhisper: E2M1 block-32 fake-quant of x and W, then x_q @ W_q^T + bias.
// M=12000 (pad 12032=47*256), K=1280, N=5120. Outputs: out[12000][5120] f32, scale_w[5120][40] f32.
//
// R10: 256x256, BK=64, 8 waves (2x4), 1 block/CU (acc in 128 AGPR, frags in 128 arch).
// Rotated-quadrant lag-1 pipeline: Q1(a0*b0) Q2(a0*b1) Q3(a1*b1) Q4(a1*b0); each
// quadrant issues only the next quadrant's missing operand (reads land during MFMA).
// ONE barrier + lgkm(0) + vmcnt(0) per K-tile (X-restage WAR + Y-stage retire).
// Only b0 is parity-ping-ponged (16 regs); a0 refills in place. Peak live frags 96.

typedef _Float16 f16;
typedef _Float16 f16x8 __attribute__((ext_vector_type(8)));
typedef float f32x4 __attribute__((ext_vector_type(4)));

#define M_ROWS 12000
#define M_PAD  12032
#define N_COLS 5120
#define K_DIM  1280
#define KB     40
#define NTN    20          // N tiles of 256

#define BAR()   asm volatile("s_barrier" ::: "memory")
#define LGKM0() asm volatile("s_waitcnt lgkmcnt(0)" ::: "memory")
#define VMCNT(N) asm volatile("s_waitcnt vmcnt(%0)" :: "i"(N) : "memory")
#define GLDS(gp, lp) __builtin_amdgcn_global_load_lds( \
    (const __attribute__((address_space(1))) unsigned*)(gp), \
    (__attribute__((address_space(3))) unsigned*)(lp), 16, 0, 0)

// ---- E2M1 nearest-level (strict > boundaries, identical to reference) ----
__device__ __forceinline__ float e2m1_level(float a) {
    float lv;
    if (a > 2.5f)       lv = (a > 3.5f) ? ((a > 5.0f) ? 6.0f : 4.0f) : 3.0f;
    else if (a > 1.25f) lv = (a > 1.75f) ? 2.0f : 1.5f;
    else                lv = (a > 0.75f) ? 1.0f : ((a > 0.25f) ? 0.5f : 0.0f);
    return lv;
}

__global__ __launch_bounds__(256) void quant_x_kernel(const float* __restrict__ x,
                                                      f16* __restrict__ xq) {
    int t = blockIdx.x * blockDim.x + threadIdx.x;
    int row = t / 160;
    int c8  = t % 160;
    f16x8 o;
    if (row < M_ROWS) {
        const float* p = x + (size_t)row * K_DIM + c8 * 8;
        float v[8];
        *(float4*)&v[0] = *(const float4*)p;
        *(float4*)&v[4] = *(const float4*)(p + 4);
        float am = 0.0f;
        #pragma unroll
        for (int i = 0; i < 8; ++i) am = fmaxf(am, fabsf(v[i]));
        am = fmaxf(am, __shfl_xor(am, 1));
        am = fmaxf(am, __shfl_xor(am, 2));
        float scale = fmaxf(am / 6.0f, 1e-12f);
        #pragma unroll
        for (int i = 0; i < 8; ++i) {
            float tq = v[i] / scale;
            float q  = copysignf(e2m1_level(fabsf(tq)), tq) * scale;
            o[i] = (f16)q;
        }
    } else {
        #pragma unroll
        for (int i = 0; i < 8; ++i) o[i] = (f16)0.0f;
    }
    *(f16x8*)(xq + (size_t)row * K_DIM + c8 * 8) = o;
}

__global__ __launch_bounds__(256) void quant_w_kernel(const float* __restrict__ w,
                                                      f16* __restrict__ wq,
                                                      float* __restrict__ scale_out) {
    int t = blockIdx.x * blockDim.x + threadIdx.x;
    int row = t / 160;
    int c8  = t % 160;
    const float* p = w + (size_t)row * K_DIM + c8 * 8;
    float v[8];
    *(float4*)&v[0] = *(const float4*)p;
    *(float4*)&v[4] = *(const float4*)(p + 4);
    float am = 0.0f;
    #pragma unroll
    for (int i = 0; i < 8; ++i) am = fmaxf(am, fabsf(v[i]));
    am = fmaxf(am, __shfl_xor(am, 1));
    am = fmaxf(am, __shfl_xor(am, 2));
    float scale = fmaxf(am / 6.0f, 1e-12f);
    if ((t & 3) == 0) scale_out[row * KB + (c8 >> 2)] = scale;
    f16x8 o;
    #pragma unroll
    for (int i = 0; i < 8; ++i) {
        float tq = v[i] / scale;
        float q  = copysignf(e2m1_level(fabsf(tq)), tq) * scale;
        o[i] = (f16)q;
    }
    *(f16x8*)(wq + (size_t)row * K_DIM + c8 * 8) = o;
}

// ---- GEMM 256x256, BK=64 ----
// LDS per buffer: A [256 rows][8 chunks of 16B] (32KB) + B same; chunk c of row r
// stored at slot (c ^ (r&7)); staging pre-swizzles the global source chunk (proven 0-conflict).

__device__ __forceinline__ void stage_half(const f16* __restrict__ g, f16* l, int tid) {
    #pragma unroll
    for (int s = 0; s < 2; ++s) {
        int j = s * 512 + tid;          // chunk 0..1023
        int r = j >> 3;
        int c = (j & 7) ^ (r & 7);
        GLDS(g + (size_t)r * K_DIM + c * 8, l + (size_t)j * 8);
    }
}

// One K64-tile. X = current buffers (and restage target for t+2); Y = next tile's buffers.
// a0 (8 b128) and b0[PAR] (4 b128) are preloaded (issued during previous tile Q3/Q4).
// Q1: issue b1(4 ds);            MFMA a0*b0 -> acc[0-3][0-1]   (compiler counts lgkm)
// Q2: issue a1(8 ds);            MFMA a0*b1 -> acc[0-3][2-3]
// Q3: lgkm0; vmcnt0; BAR; stage Xa<-t+2 (4 glds); issue b0'(4 ds from Yb);
//                                MFMA a1*b1 -> acc[4-7][2-3]
// Q4: stage Xb<-t+2 (4 glds); issue a0'(8 ds from Ya);
//                                MFMA a1*b0 -> acc[4-7][0-1]
template<int PAR, bool STAGE, bool READNEXT>
__device__ __forceinline__ void ktile64(const f16* Xa, const f16* Xb,
                                        f16* Wa, f16* Wb,
                                        const f16* Ya, const f16* Yb,
                                        const f16* gA2, const f16* gB2,
                                        f16x8 (&a0)[4][2], f16x8 (&b0)[2][2][2],
                                        f32x4 (&acc)[8][4],
                                        int tid, int arow0, int brow0, const int (&swz)[2]) {
    f16x8 b1[2][2], a1[4][2];

    // ---- Q1
    #pragma unroll
    for (int fn = 0; fn < 2; ++fn) {
        b1[fn][0] = *(const f16x8*)&Xb[(brow0 + 32 + fn * 16) * 64 + swz[0]];
        b1[fn][1] = *(const f16x8*)&Xb[(brow0 + 32 + fn * 16) * 64 + swz[1]];
    }
    __builtin_amdgcn_s_setprio(1);
    #pragma unroll
    for (int fm = 0; fm < 4; ++fm)
        #pragma unroll
        for (int fn = 0; fn < 2; ++fn) {
            acc[fm][fn] = __builtin_amdgcn_mfma_f32_16x16x32_f16(a0[fm][0], b0[PAR][fn][0], acc[fm][fn], 0, 0, 0);
            acc[fm][fn] = __builtin_amdgcn_mfma_f32_16x16x32_f16(a0[fm][1], b0[PAR][fn][1], acc[fm][fn], 0, 0, 0);
        }
    __builtin_amdgcn_s_setprio(0);

    // ---- Q2
    #pragma unroll
    for (int fm = 0; fm < 4; ++fm) {
        a1[fm][0] = *(const f16x8*)&Xa[(arow0 + 64 + fm * 16) * 64 + swz[0]];
        a1[fm][1] = *(const f16x8*)&Xa[(arow0 + 64 + fm * 16) * 64 + swz[1]];
    }
    __builtin_amdgcn_s_setprio(1);
    #pragma unroll
    for (int fm = 0; fm < 4; ++fm)
        #pragma unroll
        for (int fn = 0; fn < 2; ++fn) {
            acc[fm][fn + 2] = __builtin_amdgcn_mfma_f32_16x16x32_f16(a0[fm][0], b1[fn][0], acc[fm][fn + 2], 0, 0, 0);
            acc[fm][fn + 2] = __builtin_amdgcn_mfma_f32_16x16x32_f16(a0[fm][1], b1[fn][1], acc[fm][fn + 2], 0, 0, 0);
        }
    __builtin_amdgcn_s_setprio(0);

    // ---- Q3: all X ds_reads drained + own glds (Y staging) retired -> barrier.
    LGKM0();
    VMCNT(0);
    BAR();
    if (STAGE) { stage_half(gA2, Wa, tid); stage_half(gA2 + 128 * K_DIM, Wa + 8192, tid); }
    if (READNEXT) {
        #pragma unroll
        for (int fn = 0; fn < 2; ++fn) {
            b0[1 - PAR][fn][0] = *(const f16x8*)&Yb[(brow0 + fn * 16) * 64 + swz[0]];
            b0[1 - PAR][fn][1] = *(const f16x8*)&Yb[(brow0 + fn * 16) * 64 + swz[1]];
        }
    }
    __builtin_amdgcn_s_setprio(1);
    #pragma unroll
    for (int fm = 0; fm < 4; ++fm)
        #pragma unroll
        for (int fn = 0; fn < 2; ++fn) {
            acc[fm + 4][fn + 2] = __builtin_amdgcn_mfma_f32_16x16x32_f16(a1[fm][0], b1[fn][0], acc[fm + 4][fn + 2], 0, 0, 0);
            acc[fm + 4][fn + 2] = __builtin_amdgcn_mfma_f32_16x16x32_f16(a1[fm][1], b1[fn][1], acc[fm + 4][fn + 2], 0, 0, 0);
        }
    __builtin_amdgcn_s_setprio(0);

    // ---- Q4
    if (STAGE) { stage_half(gB2, Wb, tid); stage_half(gB2 + 128 * K_DIM, Wb + 8192, tid); }
    if (READNEXT) {
        #pragma unroll
        for (int fm = 0; fm < 4; ++fm) {
            a0[fm][0] = *(const f16x8*)&Ya[(arow0 + fm * 16) * 64 + swz[0]];
            a0[fm][1] = *(const f16x8*)&Ya[(arow0 + fm * 16) * 64 + swz[1]];
        }
    }
    __builtin_amdgcn_s_setprio(1);
    #pragma unroll
    for (int fm = 0; fm < 4; ++fm)
        #pragma unroll
        for (int fn = 0; fn < 2; ++fn) {
            acc[fm + 4][fn] = __builtin_amdgcn_mfma_f32_16x16x32_f16(a1[fm][0], b0[PAR][fn][0], acc[fm + 4][fn], 0, 0, 0);
            acc[fm + 4][fn] = __builtin_amdgcn_mfma_f32_16x16x32_f16(a1[fm][1], b0[PAR][fn][1], acc[fm + 4][fn], 0, 0, 0);
        }
    __builtin_amdgcn_s_setprio(0);
}

__global__ __launch_bounds__(512, 2) void gemm_kernel(const f16* __restrict__ A,
                                                      const f16* __restrict__ B,
                                                      const float* __restrict__ bias,
                                                      float* __restrict__ C) {
    extern __shared__ f16 sm[];            // 2 bufs x (A 16384 + B 16384 f16) = 128 KiB
    int mt = blockIdx.x / NTN;
    int nt = blockIdx.x % NTN;

    int tid  = threadIdx.x;
    int lane = tid & 63;
    int wid  = tid >> 6;
    int wr   = wid >> 2;                   // 0..1
    int wc   = wid & 3;                    // 0..3
    int l15  = lane & 15;

    int swz[2] = { (((lane >> 4)    ) ^ (lane & 7)) * 8,
                   (((lane >> 4) + 4) ^ (lane & 7)) * 8 };
    int arow0 = wr * 128 + l15;
    int brow0 = wc * 64 + l15;

    const f16* gAb = A + (size_t)(mt * 256) * K_DIM;
    const f16* gBb = B + (size_t)(nt * 256) * K_DIM;

    f16* A0 = sm;
    f16* B0 = sm + 16384;
    f16* A1 = sm + 32768;
    f16* B1 = sm + 49152;

    f32x4 acc[8][4] = {};
    f16x8 a0[4][2];
    f16x8 b0[2][2][2];

    // prologue: stage tile0 -> buf0 (8 glds), tile1 -> buf1 (8 glds); retire tile0;
    // issue tile0's first-quadrant frags (b0 then a0, matching steady retire order).
    stage_half(gAb,                A0,        tid);
    stage_half(gAb + 128 * K_DIM,  A0 + 8192, tid);
    stage_half(gBb,                B0,        tid);
    stage_half(gBb + 128 * K_DIM,  B0 + 8192, tid);
    stage_half(gAb + 64,               A1,        tid);
    stage_half(gAb + 64 + 128 * K_DIM, A1 + 8192, tid);
    stage_half(gBb + 64,               B1,        tid);
    stage_half(gBb + 64 + 128 * K_DIM, B1 + 8192, tid);
    VMCNT(8);
    BAR();
    #pragma unroll
    for (int fn = 0; fn < 2; ++fn) {
        b0[0][fn][0] = *(const f16x8*)&B0[(brow0 + fn * 16) * 64 + swz[0]];
        b0[0][fn][1] = *(const f16x8*)&B0[(brow0 + fn * 16) * 64 + swz[1]];
    }
    #pragma unroll
    for (int fm = 0; fm < 4; ++fm) {
        a0[fm][0] = *(const f16x8*)&A0[(arow0 + fm * 16) * 64 + swz[0]];
        a0[fm][1] = *(const f16x8*)&A0[(arow0 + fm * 16) * 64 + swz[1]];
    }

    // main: tiles 0..17 staged pairs; t=18 (no stage, reads next); t=19 (neither)
    for (int tt = 0; tt < 9; ++tt) {
        int t = 2 * tt;
        ktile64<0, true, true>(A0, B0, A0, B0, A1, B1,
                               gAb + (t + 2) * 64, gBb + (t + 2) * 64,
                               a0, b0, acc, tid, arow0, brow0, swz);
        ktile64<1, true, true>(A1, B1, A1, B1, A0, B0,
                               gAb + (t + 3) * 64, gBb + (t + 3) * 64,
                               a0, b0, acc, tid, arow0, brow0, swz);
    }
    ktile64<0, false, true>(A0, B0, A0, B0, A1, B1, gAb, gBb,
                            a0, b0, acc, tid, arow0, brow0, swz);   // t=18
    ktile64<1, false, false>(A1, B1, A1, B1, A0, B0, gAb, gBb,
                             a0, b0, acc, tid, arow0, brow0, swz);  // t=19

    // ---- epilogue: C = acc + bias.  C/D layout: col=lane&15, row=(lane>>4)*4+j
    int crow0 = mt * 256 + wr * 128;
    int ccol  = nt * 256 + wc * 64 + l15;
    float bz[4];
    #pragma unroll
    for (int fn = 0; fn < 4; ++fn) bz[fn] = bias[ccol + fn * 16];

    #pragma unroll
    for (int fm = 0; fm < 8; ++fm) {
        #pragma unroll
        for (int j = 0; j < 4; ++j) {
            int row = crow0 + fm * 16 + (lane >> 4) * 4 + j;
            if (row < M_ROWS) {
                float* cp = C + (size_t)row * N_COLS + ccol;
                #pragma unroll
                for (int fn = 0; fn < 4; ++fn)
                    cp[fn * 16] = acc[fm][fn][j] + bz[fn];
            }
        }
    }
}

extern "C" void kernel_launch(void* const* d_in, const int* in_sizes, int n_in,
                              void* d_out, int out_size, void* d_ws, size_t ws_size,
                              hipStream_t stream) {
    const float* x      = (const float*)d_in[0];
    const float* weight = (const float*)d_in[1];
    const float* bias   = (const float*)d_in[2];
    float* out     = (float*)d_out;
    float* scale_w = (float*)d_out + (size_t)M_ROWS * N_COLS;

    f16* xq = (f16*)d_ws;
    f16* wq = (f16*)((char*)d_ws + (size_t)M_PAD * K_DIM * sizeof(f16));

    (void)hipFuncSetAttribute((const void*)gemm_kernel,
                              hipFuncAttributeMaxDynamicSharedMemorySize, 131072);

    {
        int threads = M_PAD * (K_DIM / 8);
        quant_x_kernel<<<threads / 256, 256, 0, stream>>>(x, xq);
    }
    {
        int threads = N_COLS * (K_DIM / 8);
        quant_w_kernel<<<threads / 256, 256, 0, stream>>>(weight, wq, scale_w);
    }
    {
        int grid = (M_PAD / 256) * (N_COLS / 256);   // 47 * 20 = 940
        gemm_kernel<<<grid, 512, 131072, stream>>>(xq, wq, bias, out);
    }
}

// Round 11
// 195.247 us; speedup vs baseline: 1.6122x; 1.6122x over previous
//
#include <hip/hip_runtime.h>
#include <hip/hip_fp16.h>

// QuantizedLinearWhisper: E2M1 block-32 fake-quant of x and W, then x_q @ W_q^T + bias.
// M=12000 (pad 12032=47*256), K=1280, N=5120. Outputs: out[12000][5120] f32, scale_w[5120][40] f32.
//
// R11: faithful m201-style 8-phase schedule. 256x256, BK=64, 8 waves (2x4), 1 block/CU.
// Each phase: {stage 1 half-tile; ds-read this phase's operands; MFMA 16; BAR}.
// No cross-tile fragment registers (peak live frags = 64 regs -> no spill).
// vmcnt(4) ONLY at ends of phases 4 and 8 (publish tile 2i+1 / 2i+2), raw s_barrier,
// setprio around MFMA, XOR chunk swizzle (0 conflicts, proven R2-R6).
//
// Stage slots (WAR-verified): F1:A(2i+1).lo F2:A(2i+1).hi F3:B(2i+2).lo F4:A(2i+2).lo
// F5:A(2i+2).hi F6:B(2i+2).hi F7:B(2i+3).lo F8:B(2i+3).hi.
// Reads: F1 aLO+bLO (12), F2 bHI (4), F3 aHI (8), F4 none; F5-8 mirror on tile 2i+1.

typedef _Float16 f16;
typedef _Float16 f16x8 __attribute__((ext_vector_type(8)));
typedef float f32x4 __attribute__((ext_vector_type(4)));

#define M_ROWS 12000
#define M_PAD  12032
#define N_COLS 5120
#define K_DIM  1280
#define KB     40
#define NTN    20          // N tiles of 256

#define BAR()   asm volatile("s_barrier" ::: "memory")
#define VMCNT(N) asm volatile("s_waitcnt vmcnt(%0)" :: "i"(N) : "memory")
#define GLDS(gp, lp) __builtin_amdgcn_global_load_lds( \
    (const __attribute__((address_space(1))) unsigned*)(gp), \
    (__attribute__((address_space(3))) unsigned*)(lp), 16, 0, 0)

// ---- E2M1 nearest-level (strict > boundaries, identical to reference) ----
__device__ __forceinline__ float e2m1_level(float a) {
    float lv;
    if (a > 2.5f)       lv = (a > 3.5f) ? ((a > 5.0f) ? 6.0f : 4.0f) : 3.0f;
    else if (a > 1.25f) lv = (a > 1.75f) ? 2.0f : 1.5f;
    else                lv = (a > 0.75f) ? 1.0f : ((a > 0.25f) ? 0.5f : 0.0f);
    return lv;
}

__global__ __launch_bounds__(256) void quant_x_kernel(const float* __restrict__ x,
                                                      f16* __restrict__ xq) {
    int t = blockIdx.x * blockDim.x + threadIdx.x;
    int row = t / 160;
    int c8  = t % 160;
    f16x8 o;
    if (row < M_ROWS) {
        const float* p = x + (size_t)row * K_DIM + c8 * 8;
        float v[8];
        *(float4*)&v[0] = *(const float4*)p;
        *(float4*)&v[4] = *(const float4*)(p + 4);
        float am = 0.0f;
        #pragma unroll
        for (int i = 0; i < 8; ++i) am = fmaxf(am, fabsf(v[i]));
        am = fmaxf(am, __shfl_xor(am, 1));
        am = fmaxf(am, __shfl_xor(am, 2));
        float scale = fmaxf(am / 6.0f, 1e-12f);
        #pragma unroll
        for (int i = 0; i < 8; ++i) {
            float tq = v[i] / scale;
            float q  = copysignf(e2m1_level(fabsf(tq)), tq) * scale;
            o[i] = (f16)q;
        }
    } else {
        #pragma unroll
        for (int i = 0; i < 8; ++i) o[i] = (f16)0.0f;
    }
    *(f16x8*)(xq + (size_t)row * K_DIM + c8 * 8) = o;
}

__global__ __launch_bounds__(256) void quant_w_kernel(const float* __restrict__ w,
                                                      f16* __restrict__ wq,
                                                      float* __restrict__ scale_out) {
    int t = blockIdx.x * blockDim.x + threadIdx.x;
    int row = t / 160;
    int c8  = t % 160;
    const float* p = w + (size_t)row * K_DIM + c8 * 8;
    float v[8];
    *(float4*)&v[0] = *(const float4*)p;
    *(float4*)&v[4] = *(const float4*)(p + 4);
    float am = 0.0f;
    #pragma unroll
    for (int i = 0; i < 8; ++i) am = fmaxf(am, fabsf(v[i]));
    am = fmaxf(am, __shfl_xor(am, 1));
    am = fmaxf(am, __shfl_xor(am, 2));
    float scale = fmaxf(am / 6.0f, 1e-12f);
    if ((t & 3) == 0) scale_out[row * KB + (c8 >> 2)] = scale;
    f16x8 o;
    #pragma unroll
    for (int i = 0; i < 8; ++i) {
        float tq = v[i] / scale;
        float q  = copysignf(e2m1_level(fabsf(tq)), tq) * scale;
        o[i] = (f16)q;
    }
    *(f16x8*)(wq + (size_t)row * K_DIM + c8 * 8) = o;
}

// ---- GEMM 256x256, BK=64, 8 waves 2x4, per-wave 128x64 out ----
// LDS per tile-buffer: A [256 rows][8 chunks of 16B] (32KB) + B same; chunk c of row r
// at slot (c ^ (r&7)); stage pre-swizzles the global source chunk. 128 KiB total.

__device__ __forceinline__ void stage_half(const f16* __restrict__ g, f16* l, int tid) {
    #pragma unroll
    for (int s = 0; s < 2; ++s) {
        int j = s * 512 + tid;          // chunk 0..1023 (128 rows x 8 chunks)
        int r = j >> 3;
        int c = (j & 7) ^ (r & 7);
        GLDS(g + (size_t)r * K_DIM + c * 8, l + (size_t)j * 8);
    }
}

#define READ_A(dst, buf, rbase)                                              \
    _Pragma("unroll")                                                        \
    for (int fm = 0; fm < 4; ++fm) {                                         \
        dst[fm][0] = *(const f16x8*)&(buf)[((rbase) + fm * 16) * 64 + swz[0]]; \
        dst[fm][1] = *(const f16x8*)&(buf)[((rbase) + fm * 16) * 64 + swz[1]]; \
    }
#define READ_B(dst, buf, rbase)                                              \
    _Pragma("unroll")                                                        \
    for (int fn = 0; fn < 2; ++fn) {                                         \
        dst[fn][0] = *(const f16x8*)&(buf)[((rbase) + fn * 16) * 64 + swz[0]]; \
        dst[fn][1] = *(const f16x8*)&(buf)[((rbase) + fn * 16) * 64 + swz[1]]; \
    }
#define MFMA_Q(ma, mb, mo, no)                                               \
    __builtin_amdgcn_s_setprio(1);                                           \
    _Pragma("unroll")                                                        \
    for (int fm = 0; fm < 4; ++fm)                                           \
        _Pragma("unroll")                                                    \
        for (int fn = 0; fn < 2; ++fn) {                                     \
            acc[fm + mo][fn + no] = __builtin_amdgcn_mfma_f32_16x16x32_f16(  \
                ma[fm][0], mb[fn][0], acc[fm + mo][fn + no], 0, 0, 0);       \
            acc[fm + mo][fn + no] = __builtin_amdgcn_mfma_f32_16x16x32_f16(  \
                ma[fm][1], mb[fn][1], acc[fm + mo][fn + no], 0, 0, 0);       \
        }                                                                    \
    __builtin_amdgcn_s_setprio(0);

// One iteration = tiles 2i (buf0) and 2i+1 (buf1), stages per slot table.
// SREST gates slots F3..F8 (tiles 2i+2, 2i+3); V4 = vmcnt at end of F4.
template<bool SREST, int V4>
__device__ __forceinline__ void iter8(f16* A0, f16* B0, f16* A1, f16* B1,
                                      const f16* gA1, const f16* gA2,
                                      const f16* gB2, const f16* gB3,
                                      f32x4 (&acc)[8][4],
                                      int tid, int arow0, int brow0, const int (&swz)[2]) {
    f16x8 aLO[4][2], aHI[4][2], bLO[2][2], bHI[2][2];

    // ---- F1: stage A(2i+1).lo -> buf1; read aLO+bLO (tile 2i); Q1
    stage_half(gA1, A1, tid);
    READ_A(aLO, A0, arow0);
    READ_B(bLO, B0, brow0);
    MFMA_Q(aLO, bLO, 0, 0);
    BAR();
    // ---- F2: stage A(2i+1).hi; read bHI; Q2
    stage_half(gA1 + 128 * K_DIM, A1 + 8192, tid);
    READ_B(bHI, B0, brow0 + 32);
    MFMA_Q(aLO, bHI, 0, 2);
    BAR();
    // ---- F3: stage B(2i+2).lo -> buf0 (B0 reads done F2); read aHI; Q3
    if (SREST) stage_half(gB2, B0, tid);
    READ_A(aHI, A0, arow0 + 64);
    MFMA_Q(aHI, bHI, 4, 2);
    BAR();
    // ---- F4: stage A(2i+2).lo -> buf0 (A0 reads done F3); Q4; publish tile 2i+1
    if (SREST) stage_half(gA2, A0, tid);
    MFMA_Q(aHI, bLO, 4, 0);
    VMCNT(V4);
    BAR();
    // ---- F5: stage A(2i+2).hi; read aLO+bLO (tile 2i+1); Q1
    if (SREST) stage_half(gA2 + 128 * K_DIM, A0 + 8192, tid);
    READ_A(aLO, A1, arow0);
    READ_B(bLO, B1, brow0);
    MFMA_Q(aLO, bLO, 0, 0);
    BAR();
    // ---- F6: stage B(2i+2).hi; read bHI; Q2
    if (SREST) stage_half(gB2 + 128 * K_DIM, B0 + 8192, tid);
    READ_B(bHI, B1, brow0 + 32);
    MFMA_Q(aLO, bHI, 0, 2);
    BAR();
    // ---- F7: stage B(2i+3).lo -> buf1 (B1 reads done F6); read aHI; Q3
    if (SREST) stage_half(gB3, B1, tid);
    READ_A(aHI, A1, arow0 + 64);
    MFMA_Q(aHI, bHI, 4, 2);
    BAR();
    // ---- F8: stage B(2i+3).hi; Q4; publish tile 2i+2
    if (SREST) stage_half(gB3 + 128 * K_DIM, B1 + 8192, tid);
    MFMA_Q(aHI, bLO, 4, 0);
    if (SREST) VMCNT(4);
    BAR();
}

__global__ __launch_bounds__(512, 2) void gemm_kernel(const f16* __restrict__ A,
                                                      const f16* __restrict__ B,
                                                      const float* __restrict__ bias,
                                                      float* __restrict__ C) {
    extern __shared__ f16 sm[];            // 2 tile-bufs x (A 16384 + B 16384 f16) = 128 KiB
    int mt = blockIdx.x / NTN;
    int nt = blockIdx.x % NTN;

    int tid  = threadIdx.x;
    int lane = tid & 63;
    int wid  = tid >> 6;
    int wr   = wid >> 2;                   // 0..1
    int wc   = wid & 3;                    // 0..3
    int l15  = lane & 15;

    int swz[2] = { (((lane >> 4)    ) ^ (lane & 7)) * 8,
                   (((lane >> 4) + 4) ^ (lane & 7)) * 8 };
    int arow0 = wr * 128 + l15;
    int brow0 = wc * 64 + l15;

    const f16* gAb = A + (size_t)(mt * 256) * K_DIM;
    const f16* gBb = B + (size_t)(nt * 256) * K_DIM;

    f16* A0 = sm;
    f16* B0 = sm + 16384;
    f16* A1 = sm + 32768;
    f16* B1 = sm + 49152;

    f32x4 acc[8][4] = {};

    // prologue: stage tile0 fully (slot order B.lo, A.lo, A.hi, B.hi) + tile1's B;
    // vmcnt(4) leaves B1.lo/B1.hi in flight; A1 staged at F1/F2 of iter 0.
    stage_half(gBb,               B0,        tid);
    stage_half(gAb,               A0,        tid);
    stage_half(gAb + 128 * K_DIM, A0 + 8192, tid);
    stage_half(gBb + 128 * K_DIM, B0 + 8192, tid);
    stage_half(gBb + 64,               B1,        tid);
    stage_half(gBb + 64 + 128 * K_DIM, B1 + 8192, tid);
    VMCNT(4);
    BAR();

    for (int i = 0; i < 9; ++i) {
        const f16* gA1 = gAb + (2 * i + 1) * 64;
        const f16* gA2 = gAb + (2 * i + 2) * 64;
        const f16* gB2 = gBb + (2 * i + 2) * 64;
        const f16* gB3 = gBb + (2 * i + 3) * 64;
        iter8<true, 4>(A0, B0, A1, B1, gA1, gA2, gB2, gB3,
                       acc, tid, arow0, brow0, swz);
    }
    // last iteration (tiles 18,19): stage only A19 (F1/F2); publish with vmcnt(0)
    iter8<false, 0>(A0, B0, A1, B1, gAb + 19 * 64, gAb, gBb, gBb,
                    acc, tid, arow0, brow0, swz);

    // ---- epilogue: C = acc + bias.  C/D layout: col=lane&15, row=(lane>>4)*4+j
    int crow0 = mt * 256 + wr * 128;
    int ccol  = nt * 256 + wc * 64 + l15;
    float bz[4];
    #pragma unroll
    for (int fn = 0; fn < 4; ++fn) bz[fn] = bias[ccol + fn * 16];

    #pragma unroll
    for (int fm = 0; fm < 8; ++fm) {
        #pragma unroll
        for (int j = 0; j < 4; ++j) {
            int row = crow0 + fm * 16 + (lane >> 4) * 4 + j;
            if (row < M_ROWS) {
                float* cp = C + (size_t)row * N_COLS + ccol;
                #pragma unroll
                for (int fn = 0; fn < 4; ++fn)
                    cp[fn * 16] = acc[fm][fn][j] + bz[fn];
            }
        }
    }
}

extern "C" void kernel_launch(void* const* d_in, const int* in_sizes, int n_in,
                              void* d_out, int out_size, void* d_ws, size_t ws_size,
                              hipStream_t stream) {
    const float* x      = (const float*)d_in[0];
    const float* weight = (const float*)d_in[1];
    const float* bias   = (const float*)d_in[2];
    float* out     = (float*)d_out;
    float* scale_w = (float*)d_out + (size_t)M_ROWS * N_COLS;

    f16* xq = (f16*)d_ws;
    f16* wq = (f16*)((char*)d_ws + (size_t)M_PAD * K_DIM * sizeof(f16));

    (void)hipFuncSetAttribute((const void*)gemm_kernel,
                              hipFuncAttributeMaxDynamicSharedMemorySize, 131072);

    {
        int threads = M_PAD * (K_DIM / 8);
        quant_x_kernel<<<threads / 256, 256, 0, stream>>>(x, xq);
    }
    {
        int threads = N_COLS * (K_DIM / 8);
        quant_w_kernel<<<threads / 256, 256, 0, stream>>>(weight, wq, scale_w);
    }
    {
        int grid = (M_PAD / 256) * (N_COLS / 256);   // 47 * 20 = 940
        gemm_kernel<<<grid, 512, 131072, stream>>>(xq, wq, bias, out);
    }
}